// Round 11
// baseline (68.130 us; speedup 1.0000x reference)
//
#include <hip/hip_runtime.h>
#include <hip/hip_bf16.h>

#define B_   8
#define LQ_  128
#define LM_  512
#define D_   512
#define H_   256
#define MASKVAL -1e24f
#define PRESCALE 2.88539008177792681f  // 2*log2(e): exp2(PRESCALE*x) = e^(2x)

typedef __attribute__((ext_vector_type(8))) short bf16x8;
typedef __attribute__((ext_vector_type(4))) float f32x4;

__device__ __forceinline__ ushort f2bf(float x) {
    return __builtin_bit_cast(ushort, __float2bfloat16(x));
}

// ---------------- MFMA projection GEMM (bf16 inputs, f32 accum) ----------------
#define PBM 32
#define PBN 32
#define PBK 64
#define PLDK 88

__global__ __launch_bounds__(256) void proj_mfma(
    const float* __restrict__ query, const float* __restrict__ memory,
    const float* __restrict__ Wq, const float* __restrict__ Wm,
    const float* __restrict__ bq,
    float* __restrict__ qp, float* __restrict__ kp)
{
    __shared__ ushort As[PBM][PLDK];
    __shared__ ushort Bs[PBN][PLDK];

    const int mtile = blockIdx.x % 160;
    const int ntile = blockIdx.x / 160;
    const int n0 = ntile * PBN;
    const bool is_q = (mtile < 32);
    const float* X = is_q ? (query  + (size_t)mtile * PBM * D_)
                          : (memory + (size_t)(mtile - 32) * PBM * D_);
    const float* W = is_q ? Wq : Wm;
    float* out     = is_q ? (qp + (size_t)mtile * PBM * H_)
                          : (kp + (size_t)(mtile - 32) * PBM * H_);

    const int t = threadIdx.x;
    const int lane = t & 63, w = t >> 6;
    const int wm = (w & 1) * 16, wn = (w >> 1) * 16;
    const int ar  = t >> 4;
    const int akq = t & 15;
    const int frow = lane & 15;
    const int fkof = (lane >> 4) * 8;

    f32x4 acc = {0.f, 0.f, 0.f, 0.f};

    for (int k0 = 0; k0 < D_; k0 += PBK) {
#pragma unroll
        for (int p = 0; p < 2; ++p) {
            const int row = ar + p * 16;
            const float4 x4 = *(const float4*)(X + (size_t)row * D_ + k0 + akq * 4);
            ushort4 u4;
            u4.x = f2bf(x4.x); u4.y = f2bf(x4.y); u4.z = f2bf(x4.z); u4.w = f2bf(x4.w);
            *(ushort4*)&As[row][akq * 4] = u4;
        }
#pragma unroll
        for (int p = 0; p < 2; ++p) {
            const int L  = t + p * 256;
            const int kk = L >> 3;
            const int f4 = L & 7;
            const float4 w4 = *(const float4*)(W + (size_t)(k0 + kk) * H_ + n0 + f4 * 4);
            Bs[f4 * 4 + 0][kk] = f2bf(w4.x);
            Bs[f4 * 4 + 1][kk] = f2bf(w4.y);
            Bs[f4 * 4 + 2][kk] = f2bf(w4.z);
            Bs[f4 * 4 + 3][kk] = f2bf(w4.w);
        }
        __syncthreads();
#pragma unroll
        for (int ks = 0; ks < PBK; ks += 32) {
            bf16x8 a = *(const bf16x8*)&As[wm + frow][ks + fkof];
            bf16x8 b = *(const bf16x8*)&Bs[wn + frow][ks + fkof];
            acc = __builtin_amdgcn_mfma_f32_16x16x32_bf16(a, b, acc, 0, 0, 0);
        }
        __syncthreads();
    }

    const int col  = n0 + wn + (lane & 15);
    const int rloc = wm + (lane >> 4) * 4;
    const float bias = is_q ? bq[col] : 0.0f;
#pragma unroll
    for (int r = 0; r < 4; ++r)
        out[(size_t)(rloc + r) * H_ + col] =
            __builtin_amdgcn_exp2f((acc[r] + bias) * PRESCALE);
}

// ---------------- kernel A: raw scores ----------------
// 512 blocks x 512 threads (2 blocks/CU, 4 waves/SIMD). Block = (b, 2 q).
// q/v in pinned registers; each 16-lane group owns one m; k prefetched.
// Writes raw scores to sc[row][m] (masked m left untouched -> garbage;
// the softmax kernel substitutes MASKVAL via the mask).
#define PIN4(X) asm volatile("" : "+v"(X.x), "+v"(X.y), "+v"(X.z), "+v"(X.w))

__global__ __launch_bounds__(512, 4) void scores_kernel(
    const float* __restrict__ qp,      // [1024][256] = Eq
    const float* __restrict__ kp,      // [4096][256] = Ek
    const int*   __restrict__ mask,    // [8][512]
    const float* __restrict__ v,       // [256]
    float* __restrict__ sc)            // [1024][512]
{
    __shared__ int   mlist[512];
    __shared__ int   nact_sh;
    __shared__ float sv_sh;

    const int t = threadIdx.x;
    const int b  = blockIdx.x & 7;
    const int qg = blockIdx.x >> 3;    // 0..63
    const int rowbase = b * LQ_ + qg * 2;
    const int w = t >> 6, lane = t & 63;
    const int lane16 = lane & 15, mg = lane >> 4;
    const int col = lane16 * 4;

    if (w == 6) {
        const float4 c = *(const float4*)(v + lane * 4);
        float s = c.x + c.y + c.z + c.w;
        s += __shfl_xor(s, 1);  s += __shfl_xor(s, 2);
        s += __shfl_xor(s, 4);  s += __shfl_xor(s, 8);
        s += __shfl_xor(s, 16); s += __shfl_xor(s, 32);
        if (lane == 0) sv_sh = s;
    }
    if (w == 7) {
        unsigned base = 0;
        for (int it = 0; it < 8; ++it) {
            int m = it * 64 + lane;
            int act = (mask[b * 512 + m] == 0);
            unsigned long long bal = __ballot(act);
            if (act) {
                int pos = __popcll(bal & ((1ull << lane) - 1ull));
                mlist[base + pos] = m;
            }
            base += __popcll(bal);
        }
        if (lane == 0) nact_sh = (int)base;
    }

    float4 qreg[2][4], vreg[4];
#pragma unroll
    for (int j = 0; j < 4; ++j) {
        vreg[j] = *(const float4*)(v + j * 64 + col);
        PIN4(vreg[j]);
    }
#pragma unroll
    for (int q = 0; q < 2; ++q)
#pragma unroll
        for (int j = 0; j < 4; ++j) {
            qreg[q][j] = *(const float4*)(qp + (size_t)(rowbase + q) * 256 + j * 64 + col);
            PIN4(qreg[q][j]);
        }

    __syncthreads();
    const int nact = nact_sh;
    const float sv = sv_sh;
    if (nact == 0) return;

    const float* kbase = kp + (size_t)b * 512 * 256 + col;
    int i = w * 4 + mg;
    const int last = nact - 1;
    int mcur = mlist[i <= last ? i : last];
    float4 k0 = *(const float4*)(kbase + (size_t)mcur * 256);
    float4 k1 = *(const float4*)(kbase + (size_t)mcur * 256 + 64);
    float4 k2 = *(const float4*)(kbase + (size_t)mcur * 256 + 128);
    float4 k3 = *(const float4*)(kbase + (size_t)mcur * 256 + 192);
    const int nit = (nact + 31) >> 5;
    for (int it = 0; it < nit; ++it) {
        const int inext = i + 32;
        const int mnext = mlist[inext <= last ? inext : last];
        float4 n0, n1, n2, n3;
        if (it + 1 < nit) {
            n0 = *(const float4*)(kbase + (size_t)mnext * 256);
            n1 = *(const float4*)(kbase + (size_t)mnext * 256 + 64);
            n2 = *(const float4*)(kbase + (size_t)mnext * 256 + 128);
            n3 = *(const float4*)(kbase + (size_t)mnext * 256 + 192);
        }
        float acc0 = 0.f, acc1 = 0.f;
#define COMP(J, C) { \
        const float kk = k##J.C, vv = vreg[J].C; \
        acc0 = fmaf(vv, __builtin_amdgcn_rcpf(fmaf(qreg[0][J].C, kk, 1.f)), acc0); \
        acc1 = fmaf(vv, __builtin_amdgcn_rcpf(fmaf(qreg[1][J].C, kk, 1.f)), acc1); }
        COMP(0, x) COMP(0, y) COMP(0, z) COMP(0, w)
        COMP(1, x) COMP(1, y) COMP(1, z) COMP(1, w)
        COMP(2, x) COMP(2, y) COMP(2, z) COMP(2, w)
        COMP(3, x) COMP(3, y) COMP(3, z) COMP(3, w)
#undef COMP
#define RED(X) X += __shfl_xor(X, 1); X += __shfl_xor(X, 2); \
               X += __shfl_xor(X, 4); X += __shfl_xor(X, 8);
        RED(acc0) RED(acc1)
#undef RED
        if (lane16 == 0 && i < nact) {
            sc[(size_t)(rowbase + 0) * 512 + mcur] = fmaf(-2.f, acc0, sv);
            sc[(size_t)(rowbase + 1) * 512 + mcur] = fmaf(-2.f, acc1, sv);
        }
        i = inext; mcur = mnext;
        k0 = n0; k1 = n1; k2 = n2; k3 = n3;
    }
}

// ---------------- kernel B: softmax ----------------
// 256 blocks x 256 threads; wave w = row rowbase+w. Mask-substitute MASKVAL.
__global__ __launch_bounds__(256) void softmax_kernel(
    const float* __restrict__ sc,      // [1024][512]
    const int*   __restrict__ mask,    // [8][512]
    float* __restrict__ out_w)         // [1024][512]
{
    const int t = threadIdx.x;
    const int b  = blockIdx.x & 7;
    const int qg = blockIdx.x >> 3;    // 0..31
    const int row = b * LQ_ + qg * 4 + (t >> 6);
    const int lane = t & 63;

    float s[8], e[8];
    float mx = -INFINITY;
#pragma unroll
    for (int k = 0; k < 8; ++k) {
        const int m = lane + 64 * k;
        const int msk = mask[b * 512 + m];
        s[k] = msk ? MASKVAL : sc[(size_t)row * 512 + m];
        mx = fmaxf(mx, s[k]);
    }
#pragma unroll
    for (int off = 32; off >= 1; off >>= 1) mx = fmaxf(mx, __shfl_xor(mx, off));
    float sum = 0.0f;
#pragma unroll
    for (int k = 0; k < 8; ++k) {
        e[k] = __builtin_amdgcn_exp2f((s[k] - mx) * 1.44269504088896341f);
        sum += e[k];
    }
#pragma unroll
    for (int off = 32; off >= 1; off >>= 1) sum += __shfl_xor(sum, off);
    const float rs = __builtin_amdgcn_rcpf(sum);
#pragma unroll
    for (int k = 0; k < 8; ++k)
        out_w[(size_t)row * 512 + lane + 64 * k] = e[k] * rs;
}

// ---------------- kernel C: PV ----------------
// 256 blocks x 1024 threads (16 waves/CU). Block = (b, 4 q); thread owns
// (d = t&511, q-pair qh = t>>9 — WAVE-UNIFORM). Weights are read with
// readfirstlane'd indices -> scalar s_load (SMEM pipe, no VALU/LDS cost);
// memory loads are wave-coalesced 256B rows. m-compaction skips masked m.
__global__ __launch_bounds__(1024, 4) void pv_kernel(
    const float* __restrict__ wts,     // [1024][512] = out_w (weights)
    const float* __restrict__ memory,  // [8][512][512]
    const int*   __restrict__ mask,    // [8][512]
    float* __restrict__ out_wm)        // [1024][512]
{
    __shared__ int mlist[512];
    __shared__ int nact_sh;

    const int t = threadIdx.x;
    const int b  = blockIdx.x & 7;
    const int qg = blockIdx.x >> 3;    // 0..31
    const int rowbase = b * LQ_ + qg * 4;
    const int w = t >> 6, lane = t & 63;

    if (w == 15) {
        unsigned base = 0;
        for (int it = 0; it < 8; ++it) {
            int m = it * 64 + lane;
            int act = (mask[b * 512 + m] == 0);
            unsigned long long bal = __ballot(act);
            if (act) {
                int pos = __popcll(bal & ((1ull << lane) - 1ull));
                mlist[base + pos] = m;
            }
            base += __popcll(bal);
        }
        if (lane == 0) nact_sh = (int)base;
    }
    __syncthreads();
    const int nact = nact_sh;

    const int d  = t & 511;
    const int qh = t >> 9;             // wave-uniform
    const float* mb = memory + (size_t)b * 512 * 512 + d;
    const float* w0r = wts + (size_t)(rowbase + qh * 2 + 0) * 512;
    const float* w1r = wts + (size_t)(rowbase + qh * 2 + 1) * 512;
    float a0 = 0.f, a1 = 0.f;
    int i = 0;
    for (; i + 4 <= nact; i += 4) {
        const int m0 = __builtin_amdgcn_readfirstlane(mlist[i]);
        const int m1 = __builtin_amdgcn_readfirstlane(mlist[i + 1]);
        const int m2 = __builtin_amdgcn_readfirstlane(mlist[i + 2]);
        const int m3 = __builtin_amdgcn_readfirstlane(mlist[i + 3]);
        const float v0 = mb[(size_t)m0 * 512];
        const float v1 = mb[(size_t)m1 * 512];
        const float v2 = mb[(size_t)m2 * 512];
        const float v3 = mb[(size_t)m3 * 512];
        const float s00 = w0r[m0], s01 = w0r[m1], s02 = w0r[m2], s03 = w0r[m3];
        const float s10 = w1r[m0], s11 = w1r[m1], s12 = w1r[m2], s13 = w1r[m3];
        a0 = fmaf(s03, v3, fmaf(s02, v2, fmaf(s01, v1, fmaf(s00, v0, a0))));
        a1 = fmaf(s13, v3, fmaf(s12, v2, fmaf(s11, v1, fmaf(s10, v0, a1))));
    }
    for (; i < nact; ++i) {
        const int m0 = __builtin_amdgcn_readfirstlane(mlist[i]);
        const float v0 = mb[(size_t)m0 * 512];
        a0 = fmaf(w0r[m0], v0, a0);
        a1 = fmaf(w1r[m0], v0, a1);
    }
    out_wm[(size_t)(rowbase + qh * 2 + 0) * 512 + d] = a0;
    out_wm[(size_t)(rowbase + qh * 2 + 1) * 512 + d] = a1;
}

extern "C" void kernel_launch(void* const* d_in, const int* in_sizes, int n_in,
                              void* d_out, int out_size, void* d_ws, size_t ws_size,
                              hipStream_t stream) {
    const float* query  = (const float*)d_in[0];
    const float* memory = (const float*)d_in[1];
    const int*   mask   = (const int*)  d_in[2];
    const float* Wq     = (const float*)d_in[3];
    const float* bq     = (const float*)d_in[4];
    const float* Wm     = (const float*)d_in[5];
    const float* v      = (const float*)d_in[6];

    float* out_wm = (float*)d_out;                         // [1024][512]
    float* out_w  = out_wm + (size_t)B_ * LQ_ * D_;        // [1024][512]

    float* qp = (float*)d_ws;                              // [1024][256] = Eq
    float* kp = qp + (size_t)B_ * LQ_ * H_;                // [4096][256] = Ek
    float* sc = kp + (size_t)B_ * LM_ * H_;                // [1024][512] raw scores

    hipLaunchKernelGGL(proj_mfma, dim3(160 * (H_ / PBN)), dim3(256), 0, stream,
                       query, memory, Wq, Wm, bq, qp, kp);
    hipLaunchKernelGGL(scores_kernel, dim3(B_ * (LQ_ / 2)), dim3(512), 0, stream,
                       qp, kp, mask, v, sc);
    hipLaunchKernelGGL(softmax_kernel, dim3(B_ * (LQ_ / 4)), dim3(256), 0, stream,
                       sc, mask, out_w);
    hipLaunchKernelGGL(pv_kernel, dim3(B_ * (LQ_ / 4)), dim3(1024), 0, stream,
                       out_w, memory, mask, out_wm);
}

// Round 12
// 46.657 us; speedup vs baseline: 1.4602x; 1.4602x over previous
//
#include <hip/hip_runtime.h>
#include <hip/hip_bf16.h>

#define B_   8
#define LQ_  128
#define LM_  512
#define D_   512
#define H_   256
#define MASKVAL -1e24f
#define PRESCALE 2.88539008177792681f  // 2*log2(e): exp2(PRESCALE*x) = e^(2x)

typedef __attribute__((ext_vector_type(8))) short bf16x8;
typedef __attribute__((ext_vector_type(4))) float f32x4;

__device__ __forceinline__ ushort f2bf(float x) {
    return __builtin_bit_cast(ushort, __float2bfloat16(x));
}

// ---------------- MFMA projection GEMM (bf16 inputs, f32 accum) ----------------
// Epilogue stores E = exp2(PRESCALE * (X@W + bias)); attention computes
// sigma(q+k) = rcp(Eq*Ek + 1), batched 4 sigmoids per rcp.
#define PBM 32
#define PBN 32
#define PBK 64
#define PLDK 88

__global__ __launch_bounds__(256) void proj_mfma(
    const float* __restrict__ query, const float* __restrict__ memory,
    const float* __restrict__ Wq, const float* __restrict__ Wm,
    const float* __restrict__ bq,
    float* __restrict__ qp, float* __restrict__ kp)
{
    __shared__ ushort As[PBM][PLDK];
    __shared__ ushort Bs[PBN][PLDK];

    const int mtile = blockIdx.x % 160;
    const int ntile = blockIdx.x / 160;
    const int n0 = ntile * PBN;
    const bool is_q = (mtile < 32);
    const float* X = is_q ? (query  + (size_t)mtile * PBM * D_)
                          : (memory + (size_t)(mtile - 32) * PBM * D_);
    const float* W = is_q ? Wq : Wm;
    float* out     = is_q ? (qp + (size_t)mtile * PBM * H_)
                          : (kp + (size_t)(mtile - 32) * PBM * H_);

    const int t = threadIdx.x;
    const int lane = t & 63, w = t >> 6;
    const int wm = (w & 1) * 16, wn = (w >> 1) * 16;
    const int ar  = t >> 4;
    const int akq = t & 15;
    const int frow = lane & 15;
    const int fkof = (lane >> 4) * 8;

    f32x4 acc = {0.f, 0.f, 0.f, 0.f};

    for (int k0 = 0; k0 < D_; k0 += PBK) {
#pragma unroll
        for (int p = 0; p < 2; ++p) {
            const int row = ar + p * 16;
            const float4 x4 = *(const float4*)(X + (size_t)row * D_ + k0 + akq * 4);
            ushort4 u4;
            u4.x = f2bf(x4.x); u4.y = f2bf(x4.y); u4.z = f2bf(x4.z); u4.w = f2bf(x4.w);
            *(ushort4*)&As[row][akq * 4] = u4;
        }
#pragma unroll
        for (int p = 0; p < 2; ++p) {
            const int L  = t + p * 256;
            const int kk = L >> 3;
            const int f4 = L & 7;
            const float4 w4 = *(const float4*)(W + (size_t)(k0 + kk) * H_ + n0 + f4 * 4);
            Bs[f4 * 4 + 0][kk] = f2bf(w4.x);
            Bs[f4 * 4 + 1][kk] = f2bf(w4.y);
            Bs[f4 * 4 + 2][kk] = f2bf(w4.z);
            Bs[f4 * 4 + 3][kk] = f2bf(w4.w);
        }
        __syncthreads();
#pragma unroll
        for (int ks = 0; ks < PBK; ks += 32) {
            bf16x8 a = *(const bf16x8*)&As[wm + frow][ks + fkof];
            bf16x8 b = *(const bf16x8*)&Bs[wn + frow][ks + fkof];
            acc = __builtin_amdgcn_mfma_f32_16x16x32_bf16(a, b, acc, 0, 0, 0);
        }
        __syncthreads();
    }

    const int col  = n0 + wn + (lane & 15);
    const int rloc = wm + (lane >> 4) * 4;
    const float bias = is_q ? bq[col] : 0.0f;
#pragma unroll
    for (int r = 0; r < 4; ++r)
        out[(size_t)(rloc + r) * H_ + col] =
            __builtin_amdgcn_exp2f((acc[r] + bias) * PRESCALE);
}

// ---------------- fused score/softmax/PV (R7-best structure) ----------------
// One block = (b, 2 q). 512 threads = 8 waves; 512 blocks = 2 blocks/CU.
// QUAD trick: 4 sigmoids share ONE rcp:
//   u_c = fma(q_c,k_c,1);  sum_c v_c/u_c = (n12*d34 + n34*d12) / (d12*d34)
__global__ __launch_bounds__(512, 4) void attn_kernel(
    const float* __restrict__ qp,      // [1024][256] = Eq
    const float* __restrict__ kp,      // [4096][256] = Ek
    const float* __restrict__ memory,  // [8][512][512]
    const int*   __restrict__ mask,    // [8][512]
    const float* __restrict__ v,       // [256]
    float* __restrict__ out_wm,        // [1024][512]
    float* __restrict__ out_w)         // [1024][512]
{
    __shared__ float scores[2][512];   // 4 KB
    __shared__ float qsw[2][256];      // 2 KB
    __shared__ float vs[256];          // 1 KB
    __shared__ int   mlist[512];       // 2 KB
    __shared__ int   nact_sh;
    __shared__ float sv_sh;

    const int t = threadIdx.x;
    const int b  = blockIdx.x & 7;     // all blocks of batch b -> XCD b
    const int qg = blockIdx.x >> 3;    // 0..63
    const int rowbase = b * LQ_ + qg * 2;
    const int w = t >> 6, lane = t & 63;

    ((float2*)&scores[0][0])[t] = make_float2(MASKVAL, MASKVAL);

    if (t < 128) {                      // stage Eq rows
        const int q = t >> 6, c4 = t & 63;
        *(float4*)&qsw[q][c4 * 4] = *(const float4*)(qp + (size_t)(rowbase + q) * 256 + c4 * 4);
    } else if (t < 192) {               // stage v + sv
        const int l = t - 128;
        const float4 c = *(const float4*)(v + l * 4);
        *(float4*)&vs[l * 4] = c;
        float s = c.x + c.y + c.z + c.w;
        s += __shfl_xor(s, 1);  s += __shfl_xor(s, 2);
        s += __shfl_xor(s, 4);  s += __shfl_xor(s, 8);
        s += __shfl_xor(s, 16); s += __shfl_xor(s, 32);
        if (l == 0) sv_sh = s;
    }
    if (w == 7) {                       // compact active-m list
        unsigned base = 0;
        for (int it = 0; it < 8; ++it) {
            int m = it * 64 + lane;
            int act = (mask[b * 512 + m] == 0);
            unsigned long long bal = __ballot(act);
            if (act) {
                int pos = __popcll(bal & ((1ull << lane) - 1ull));
                mlist[base + pos] = m;
            }
            base += __popcll(bal);
        }
        if (lane == 0) nact_sh = (int)base;
    }
    __syncthreads();
    const int nact = nact_sh;
    const float sv = sv_sh;

    // ---- phase 1 ----
    {
        const int lane16 = lane & 15;
        const int col = lane16 * 4;
        const int base_i = w * 4 + (lane >> 4);   // 0..31
        const int nit = (nact + 63) >> 6;
        for (int it = 0; it < nit; ++it) {
            const int ia = it * 64 + base_i;
            const int ib = ia + 32;
            const bool acta = ia < nact, actb = ib < nact;
            const int ma = mlist[acta ? ia : 0];
            const int mb = mlist[actb ? ib : 0];
            const float* ka = kp + (size_t)(b * 512 + ma) * 256 + col;
            const float* kb = kp + (size_t)(b * 512 + mb) * 256 + col;
            const f32x4 kA0 = *(const f32x4*)(ka);
            const f32x4 kA1 = *(const f32x4*)(ka + 64);
            const f32x4 kA2 = *(const f32x4*)(ka + 128);
            const f32x4 kA3 = *(const f32x4*)(ka + 192);
            const f32x4 kB0 = *(const f32x4*)(kb);
            const f32x4 kB1 = *(const f32x4*)(kb + 64);
            const f32x4 kB2 = *(const f32x4*)(kb + 128);
            const f32x4 kB3 = *(const f32x4*)(kb + 192);
            float a0 = 0.f, a1 = 0.f, b0 = 0.f, b1 = 0.f;
            // QUAD: sum_{c in quad} v_c * rcp(fma(q_c,k_c,1)) with one rcp
#define QUAD(ACC, Q, K, VV) { \
            const float u_ = fmaf(Q.x, K.x, 1.f); \
            const float w_ = fmaf(Q.y, K.y, 1.f); \
            const float y_ = fmaf(Q.z, K.z, 1.f); \
            const float z_ = fmaf(Q.w, K.w, 1.f); \
            const float d12_ = u_ * w_, d34_ = y_ * z_; \
            const float n12_ = fmaf(VV.y, u_, VV.x * w_); \
            const float n34_ = fmaf(VV.w, y_, VV.z * z_); \
            const float N_ = fmaf(n12_, d34_, n34_ * d12_); \
            ACC = fmaf(N_, __builtin_amdgcn_rcpf(d12_ * d34_), ACC); }
#define JBLK(J, KA, KB) { \
            const f32x4 vv = *(const f32x4*)&vs[J * 64 + col]; \
            const f32x4 q0 = *(const f32x4*)&qsw[0][J * 64 + col]; \
            const f32x4 q1 = *(const f32x4*)&qsw[1][J * 64 + col]; \
            QUAD(a0, q0, KA, vv) QUAD(a1, q1, KA, vv) \
            QUAD(b0, q0, KB, vv) QUAD(b1, q1, KB, vv) }
            JBLK(0, kA0, kB0)
            JBLK(1, kA1, kB1)
            JBLK(2, kA2, kB2)
            JBLK(3, kA3, kB3)
#undef JBLK
#undef QUAD
#define RED(X) X += __shfl_xor(X, 1); X += __shfl_xor(X, 2); \
               X += __shfl_xor(X, 4); X += __shfl_xor(X, 8);
            RED(a0) RED(a1) RED(b0) RED(b1)
#undef RED
            if (lane16 == 0) {
                if (acta) {
                    scores[0][ma] = fmaf(-2.f, a0, sv);
                    scores[1][ma] = fmaf(-2.f, a1, sv);
                }
                if (actb) {
                    scores[0][mb] = fmaf(-2.f, b0, sv);
                    scores[1][mb] = fmaf(-2.f, b1, sv);
                }
            }
        }
    }
    __syncthreads();

    // ---- phase 2: softmax per q (waves 0..1) ----
    if (w < 2) {
        const int q = w, row = rowbase + q;
        float s[8], e[8];
        float mx = -INFINITY;
#pragma unroll
        for (int k = 0; k < 8; ++k) { s[k] = scores[q][lane + 64 * k]; mx = fmaxf(mx, s[k]); }
#pragma unroll
        for (int off = 32; off >= 1; off >>= 1) mx = fmaxf(mx, __shfl_xor(mx, off));
        float sum = 0.0f;
#pragma unroll
        for (int k = 0; k < 8; ++k) {
            e[k] = __builtin_amdgcn_exp2f((s[k] - mx) * 1.44269504088896341f);
            sum += e[k];
        }
#pragma unroll
        for (int off = 32; off >= 1; off >>= 1) sum += __shfl_xor(sum, off);
        float rs = __builtin_amdgcn_rcpf(sum);
#pragma unroll
        for (int k = 0; k < 8; ++k) {
            float wt = e[k] * rs;
            scores[q][lane + 64 * k] = wt;
            out_w[(size_t)row * 512 + lane + 64 * k] = wt;
        }
    }
    __syncthreads();

    // ---- phase 3: weighted_memory; d = t, both q per thread, 4-deep MLP ----
    {
        const int d = t;
        const float* mb = memory + (size_t)b * 512 * 512 + d;
        const float* s0 = scores[0];
        const float* s1 = scores[1];
        float a0 = 0.f, a1 = 0.f;
        int i = 0;
        for (; i + 4 <= nact; i += 4) {
            const int m0 = mlist[i], m1 = mlist[i + 1], m2 = mlist[i + 2], m3 = mlist[i + 3];
            const float v0 = mb[(size_t)m0 * 512];
            const float v1 = mb[(size_t)m1 * 512];
            const float v2 = mb[(size_t)m2 * 512];
            const float v3 = mb[(size_t)m3 * 512];
            a0 = fmaf(s0[m3], v3, fmaf(s0[m2], v2, fmaf(s0[m1], v1, fmaf(s0[m0], v0, a0))));
            a1 = fmaf(s1[m3], v3, fmaf(s1[m2], v2, fmaf(s1[m1], v1, fmaf(s1[m0], v0, a1))));
        }
        for (; i < nact; ++i) {
            const int m0 = mlist[i];
            const float v0 = mb[(size_t)m0 * 512];
            a0 = fmaf(s0[m0], v0, a0);
            a1 = fmaf(s1[m0], v0, a1);
        }
        out_wm[(size_t)(rowbase + 0) * 512 + d] = a0;
        out_wm[(size_t)(rowbase + 1) * 512 + d] = a1;
    }
}

extern "C" void kernel_launch(void* const* d_in, const int* in_sizes, int n_in,
                              void* d_out, int out_size, void* d_ws, size_t ws_size,
                              hipStream_t stream) {
    const float* query  = (const float*)d_in[0];
    const float* memory = (const float*)d_in[1];
    const int*   mask   = (const int*)  d_in[2];
    const float* Wq     = (const float*)d_in[3];
    const float* bq     = (const float*)d_in[4];
    const float* Wm     = (const float*)d_in[5];
    const float* v      = (const float*)d_in[6];

    float* out_wm = (float*)d_out;                         // [1024][512]
    float* out_w  = out_wm + (size_t)B_ * LQ_ * D_;        // [1024][512]

    float* qp = (float*)d_ws;                              // [1024][256] = Eq
    float* kp = qp + (size_t)B_ * LQ_ * H_;                // [4096][256] = Ek

    hipLaunchKernelGGL(proj_mfma, dim3(160 * (H_ / PBN)), dim3(256), 0, stream,
                       query, memory, Wq, Wm, bq, qp, kp);
    hipLaunchKernelGGL(attn_kernel, dim3(B_ * (LQ_ / 2)), dim3(512), 0, stream,
                       qp, kp, memory, mask, v, out_wm, out_w);
}